// Round 13
// baseline (497.412 us; speedup 1.0000x reference)
//
#include <hip/hip_runtime.h>

// MFMA-based fully-fused 5-layer bidirectional GRU -- dual-chain waves.
//
// r12 verdict: deep prefetch null -> residual 24% idle = all 4 resident
// waves co-stalled on their single serial chain (MFMA -> 6-deep trans tree
// -> pack -> MFMA). Fix: TWO independent recurrence chains per wave
// (64 batch cols/block: A = cols 0..31, B = cols 32..63, shared weights).
// Compiler statically interleaves the chains -> deterministic intra-wave
// ILP covers each chain's latency. LDS 38.4KB -> 4 blocks/CU -> 2 waves/SIMD
// x 2 chains = same 4 chains/SIMD and same 4.9MB/XCD G footprint (the
// r9-validated L2 budget), but waves are now self-covering.
//
// Exchange-free B layout (r11, verified): D row = 4u+g -> half0 owns units
// {0,2,4}, half1 {1,3}. B h-slots match ownership: k5,6,7 = h_u0,u2,u4
// (half0 elems 5..7), k13,14 = h_u1,u3 (half1 elems 5..6); x channels at
// k0..4 & k8..12, idx=(k<8?k:k-3), concat col j=(idx&1)*5+(idx>>1). No
// cross-lane h movement. B dwords via 2 layer-constant v_perm + 1 on-chain.
//
// A (32x16 const): row = 4u+g, g in {r,z,i_n,h_n}, rows 20-31 zero; same
// k-rule as B. C = bias fragment, quad q -> u = 2q+half (r2-verified).
// i_n/h_n separate rows so n = tanh(i_n + r*h_n) exact; exp2 scales folded.
//
// Structure: block = 128 thr = 2 waves (wave0 fwd, wave1 bwd), 64 batch.
// One 38.4KB LDS buffer + one 38.4KB global buffer per block. Dataflow:
// L0: x->S; L1: S->G; L2: G->S; L3: S->G; L4: G->out (bwd: 1 step).
// Sequences: f16 pair-planes seq[t][unit][64 cols], fwd lo / bwd hi halfword.

#define NB 262144
#define T 30
#define NBLK (NB / 64)
#define SEQW (T * 5 * 64)          // u32 per per-block sequence buffer

typedef _Float16 f16x8 __attribute__((ext_vector_type(8)));
typedef float f32x16 __attribute__((ext_vector_type(16)));

__device__ unsigned g_seq[(unsigned long long)NBLK * SEQW];   // 157 MB

#define SIG_SCALE  (-1.4426950408889634f)   // -log2(e)
#define TANH_SCALE ( 2.8853900817779268f)   // 2*log2(e)

__device__ __forceinline__ float sig_s(float xs) {
    // x pre-scaled by -log2e: sigmoid(orig) = 1/(1+2^x)
    return __builtin_amdgcn_rcpf(1.0f + __builtin_amdgcn_exp2f(xs));
}
__device__ __forceinline__ float tanh_s(float xs) {
    // x pre-scaled by 2*log2e: tanh(orig) = 1 - 2/(1+2^x)
    return fmaf(-2.0f, __builtin_amdgcn_rcpf(1.0f + __builtin_amdgcn_exp2f(xs)), 1.0f);
}
__device__ __forceinline__ unsigned hbits(_Float16 a) {
    union { _Float16 f; unsigned short s; } u; u.f = a;
    return (unsigned)u.s;
}
__device__ __forceinline__ unsigned packh(_Float16 a, _Float16 b) {
    return hbits(a) | (hbits(b) << 16);
}

// One direction of one layer, TWO independent 32-col chains (A: cols 0..31,
// B: cols 32..63). seqR/seqW: [T][5][64] u32 pair-plane buffers (LDS or
// global per G_R); xg: per-block x base (layer 0 only).
template <bool IS_L0, int NT, bool WRITE, bool STORE, bool G_R>
__device__ __forceinline__ void run_layer(
    const float* __restrict__ wih, const float* __restrict__ whh,
    const float* __restrict__ bih, const float* __restrict__ bhh,
    const unsigned* seqR, unsigned* seqW, const float* xg,
    float* outp, const int d, const int lane)
{
    const int lr   = lane & 31;    // A row / B,D column (batch, chain A)
    const int half = lane >> 5;    // k-half for A/B; D-row half bit

    // ---- A fragment: row lr = 4u+g (shared by both chains) ----
    const int u_r = lr >> 2;
    const int g   = lr & 3;        // 0=r 1=z 2=i_n 3=h_n
    const bool rv = lr < 20;       // rows 20-31 zero

    f16x8 af;
#pragma unroll
    for (int e = 0; e < 8; e++) {
        const int k = 8 * half + e;           // elem e <-> k = 8*half + e
        float v = 0.f;
        if (rv) {
            if (!IS_L0) {
                if (k <= 4 || (k >= 8 && k <= 12)) {      // x channels
                    const int idx = (k < 8) ? k : (k - 3);
                    const int j = (idx & 1) * 5 + (idx >> 1);   // concat col
                    if (g == 0)      v = SIG_SCALE  * wih[u_r * 10 + j];
                    else if (g == 1) v = SIG_SCALE  * wih[(5 + u_r) * 10 + j];
                    else if (g == 2) v = TANH_SCALE * wih[(10 + u_r) * 10 + j];
                } else if (k >= 5 && k <= 7) {            // h_u0,u2,u4
                    const int uh = 2 * (k - 5);
                    if (g == 0)      v = SIG_SCALE  * whh[u_r * 5 + uh];
                    else if (g == 1) v = SIG_SCALE  * whh[(5 + u_r) * 5 + uh];
                    else if (g == 3) v = TANH_SCALE * whh[(10 + u_r) * 5 + uh];
                } else if (k == 13 || k == 14) {          // h_u1,u3
                    const int uh = 2 * (k - 13) + 1;
                    if (g == 0)      v = SIG_SCALE  * whh[u_r * 5 + uh];
                    else if (g == 1) v = SIG_SCALE  * whh[(5 + u_r) * 5 + uh];
                    else if (g == 3) v = TANH_SCALE * whh[(10 + u_r) * 5 + uh];
                }
            } else {
                if (k == 0) {                             // input dim 1
                    if (g == 0)      v = SIG_SCALE  * wih[u_r];
                    else if (g == 1) v = SIG_SCALE  * wih[5 + u_r];
                    else if (g == 2) v = TANH_SCALE * wih[10 + u_r];
                } else if (k >= 5 && k <= 7) {
                    const int uh = 2 * (k - 5);
                    if (g == 0)      v = SIG_SCALE  * whh[u_r * 5 + uh];
                    else if (g == 1) v = SIG_SCALE  * whh[(5 + u_r) * 5 + uh];
                    else if (g == 3) v = TANH_SCALE * whh[(10 + u_r) * 5 + uh];
                } else if (k == 13 || k == 14) {
                    const int uh = 2 * (k - 13) + 1;
                    if (g == 0)      v = SIG_SCALE  * whh[u_r * 5 + uh];
                    else if (g == 1) v = SIG_SCALE  * whh[(5 + u_r) * 5 + uh];
                    else if (g == 3) v = TANH_SCALE * whh[(10 + u_r) * 5 + uh];
                }
            }
        }
        af[e] = (_Float16)v;
    }

    // ---- bias fragment (C): quad q -> unit u = 2q+half (r2-verified) ----
    f32x16 bc;
#pragma unroll
    for (int q = 0; q < 4; q++) {
        const int u = 2 * q + half;
        float b0 = 0.f, b1 = 0.f, b2 = 0.f, b3 = 0.f;
        if (q < 3 && u < 5) {
            b0 = SIG_SCALE  * (bih[u] + bhh[u]);
            b1 = SIG_SCALE  * (bih[5 + u] + bhh[5 + u]);
            b2 = TANH_SCALE * bih[10 + u];
            b3 = TANH_SCALE * bhh[10 + u];
        }
        bc[4 * q + 0] = b0; bc[4 * q + 1] = b1;
        bc[4 * q + 2] = b2; bc[4 * q + 3] = b3;
    }

    // ---- B-assembly selectors (layer-constant; perm: sel<4 -> 2nd arg) ----
    const unsigned S01 = half ? 0x05040302u : 0x03020100u;
    const unsigned S2  = half ? 0x05040302u : 0x05040100u;

    // ---- step state ----
    const int sdir = d ? -1 : 1;
    const int p0   = d ? (T - 1) : 0;
    // [t][u][64]: t-stride 320 u32, plane stride 64 u32.
    // half0 reads planes 0,1,2 (offs 0/64/128); half1 planes 2,3,4 (+128).
    const unsigned* rbA = seqR + p0 * 320 + lr + (half ? 128 : 0);
    _Float16* wbase = (_Float16*)seqW + p0 * 640 + lr * 2 + d;  // chain B at +64
    const int rstep = sdir * 320, wstep = sdir * 640;

    // per chain: h0 = u(half), h1 = u(2+half), h2 = u4 (half0; dead on half1)
    float h0A = 0.f, h1A = 0.f, h2A = 0.f;
    float h0B = 0.f, h1B = 0.f, h2B = 0.f;
    unsigned hw2A = 0, hw3A = 0, hw2B = 0, hw3B = 0;

    auto stepAB = [&](unsigned paA, unsigned pbA, unsigned pcA,
                      unsigned paB, unsigned pbB, unsigned pcB,
                      unsigned xvA, unsigned xvB) {
        union { f16x8 v; unsigned u[4]; } BA, BB;
        if constexpr (!IS_L0) {
            BA.u[0] = __builtin_amdgcn_perm(pbA, paA, S01);
            BA.u[1] = __builtin_amdgcn_perm(pcA, pbA, S01);
            BA.u[2] = __builtin_amdgcn_perm(hw2A, pcA, S2);
            BB.u[0] = __builtin_amdgcn_perm(pbB, paB, S01);
            BB.u[1] = __builtin_amdgcn_perm(pcB, pbB, S01);
            BB.u[2] = __builtin_amdgcn_perm(hw2B, pcB, S2);
        } else {
            BA.u[0] = half ? 0u : xvA; BA.u[1] = 0u; BA.u[2] = hw2A << 16;
            BB.u[0] = half ? 0u : xvB; BB.u[1] = 0u; BB.u[2] = hw2B << 16;
        }
        BA.u[3] = hw3A;                    // dead k-rows are 0 in A
        BB.u[3] = hw3B;

        const f32x16 DA = __builtin_amdgcn_mfma_f32_32x32x16_f16(af, BA.v, bc, 0, 0, 0);
        const f32x16 DB = __builtin_amdgcn_mfma_f32_32x32x16_f16(af, BB.v, bc, 0, 0, 0);

        // chain A activations (quad q = unit 2q+half)
        float r, z, n;
        r = sig_s(DA[0]); z = sig_s(DA[1]);
        n = tanh_s(fmaf(r, DA[3], DA[2]));
        h0A = fmaf(z, h0A - n, n);
        r = sig_s(DA[4]); z = sig_s(DA[5]);
        n = tanh_s(fmaf(r, DA[7], DA[6]));
        h1A = fmaf(z, h1A - n, n);
        r = sig_s(DA[8]); z = sig_s(DA[9]);
        n = tanh_s(fmaf(r, DA[11], DA[10]));
        h2A = fmaf(z, h2A - n, n);         // zero rows on half1: harmless 0

        // chain B activations
        r = sig_s(DB[0]); z = sig_s(DB[1]);
        n = tanh_s(fmaf(r, DB[3], DB[2]));
        h0B = fmaf(z, h0B - n, n);
        r = sig_s(DB[4]); z = sig_s(DB[5]);
        n = tanh_s(fmaf(r, DB[7], DB[6]));
        h1B = fmaf(z, h1B - n, n);
        r = sig_s(DB[8]); z = sig_s(DB[9]);
        n = tanh_s(fmaf(r, DB[11], DB[10]));
        h2B = fmaf(z, h2B - n, n);

        const _Float16 q0A = (_Float16)h0A, q1A = (_Float16)h1A, q2A = (_Float16)h2A;
        const _Float16 q0B = (_Float16)h0B, q1B = (_Float16)h1B, q2B = (_Float16)h2B;
        hw2A = hbits(q0A); hw3A = packh(q1A, q2A);
        hw2B = hbits(q0B); hw3B = packh(q1B, q2B);

        if constexpr (WRITE) {
            wbase[half * 128]       = q0A;         // plane u = half
            wbase[(2 + half) * 128] = q1A;         // plane u = 2+half
            if (!half) wbase[4 * 128] = q2A;       // plane u = 4
            _Float16* wb2 = wbase + 64;            // chain B cols
            wb2[half * 128]       = q0B;
            wb2[(2 + half) * 128] = q1B;
            if (!half) wb2[4 * 128] = q2B;
            wbase += wstep;
        }
    };

    if constexpr (IS_L0) {
        // x direct from global, 1-step prefetch per chain
        const float* xpA = xg + lr * T + p0;
        const float* xpB = xpA + 32 * T;
        float xfA = *xpA, xfB = *xpB;
        for (int s = 0; s < NT; s++) {
            const unsigned xvA = hbits((_Float16)xfA);
            const unsigned xvB = hbits((_Float16)xfB);
            if (s + 1 < NT) { xpA += sdir; xfA = *xpA; xpB += sdir; xfB = *xpB; }
            stepAB(0u, 0u, 0u, 0u, 0u, 0u, xvA, xvB);
        }
    } else if constexpr (!G_R) {
        // LDS reads, 1-step prefetch
        const unsigned* rb = rbA;
        unsigned a0 = rb[0], a1 = rb[64], a2 = rb[128];
        unsigned a3 = rb[32], a4 = rb[96], a5 = rb[160];
        for (int s = 0; s < NT; s++) {
            const unsigned t0 = a0, t1 = a1, t2 = a2, t3 = a3, t4 = a4, t5 = a5;
            if (s + 1 < NT) {
                rb += rstep;
                a0 = rb[0]; a1 = rb[64]; a2 = rb[128];
                a3 = rb[32]; a4 = rb[96]; a5 = rb[160];
            }
            stepAB(t0, t1, t2, t3, t4, t5, 0u, 0u);
        }
    } else if constexpr (NT == 1) {
        // layer-4 bwd: single step
        stepAB(rbA[0], rbA[64], rbA[128], rbA[32], rbA[96], rbA[160], 0u, 0u);
    } else {
        // global reads: two reg sets, prefetch 2 positions ahead (vmcnt);
        // chain-B compute additionally covers chain-A miss latency
        const unsigned* rn = rbA;
        unsigned a0 = rn[0], a1 = rn[64], a2 = rn[128];
        unsigned a3 = rn[32], a4 = rn[96], a5 = rn[160];
        rn += rstep;
        unsigned b0 = rn[0], b1 = rn[64], b2 = rn[128];
        unsigned b3 = rn[32], b4 = rn[96], b5 = rn[160];
        rn += rstep;
        for (int s = 0; s < NT; s += 2) {
            stepAB(a0, a1, a2, a3, a4, a5, 0u, 0u);
            if (s + 2 < NT) {
                a0 = rn[0]; a1 = rn[64]; a2 = rn[128];
                a3 = rn[32]; a4 = rn[96]; a5 = rn[160];
                rn += rstep;
            }
            stepAB(b0, b1, b2, b3, b4, b5, 0u, 0u);
            if (s + 3 < NT) {
                b0 = rn[0]; b1 = rn[64]; b2 = rn[128];
                b3 = rn[32]; b4 = rn[96]; b5 = rn[160];
                rn += rstep;
            }
        }
    }

    if constexpr (STORE) {               // ys[T-1] for this direction
        outp[half]     = h0A;
        outp[2 + half] = h1A;
        if (!half) outp[4] = h2A;
        float* op2 = outp + 320;         // chain B: col + 32 -> +32*10
        op2[half]     = h0B;
        op2[2 + half] = h1B;
        if (!half) op2[4] = h2B;
    }
}

__global__ void __launch_bounds__(128, 2) gru_all(
    const float* __restrict__ x,
    const float* __restrict__ wih0, const float* __restrict__ whh0,
    const float* __restrict__ bih0, const float* __restrict__ bhh0,
    const float* __restrict__ wihL, const float* __restrict__ whhL,
    const float* __restrict__ bihL, const float* __restrict__ bhhL,
    float* __restrict__ out)
{
    __shared__ unsigned S[T][5][64];             // 38400 B -> 4 blocks/CU

    const int tid  = threadIdx.x;
    const int d    = tid >> 6;                   // wave0 = fwd, wave1 = bwd
    const int lane = tid & 63;
    const int lr   = lane & 31;
    const long base = (long)blockIdx.x * 64;

    const float* xg = x + base * T;
    unsigned* G = g_seq + (unsigned long long)blockIdx.x * SEQW;

    // L0: x -> S
    run_layer<true, T, true, false, false>(
        wih0 + d * 15, whh0 + d * 75, bih0 + d * 15, bhh0 + d * 15,
        nullptr, &S[0][0][0], xg, nullptr, d, lane);
    __syncthreads();

    // L1: S -> G
    run_layer<false, T, true, false, false>(
        wihL + (0 + d) * 150, whhL + (0 + d) * 75, bihL + (0 + d) * 15, bhhL + (0 + d) * 15,
        &S[0][0][0], G, nullptr, nullptr, d, lane);
    __syncthreads();

    // L2: G -> S
    run_layer<false, T, true, false, true>(
        wihL + (2 + d) * 150, whhL + (2 + d) * 75, bihL + (2 + d) * 15, bhhL + (2 + d) * 15,
        G, &S[0][0][0], nullptr, nullptr, d, lane);
    __syncthreads();

    // L3: S -> G
    run_layer<false, T, true, false, false>(
        wihL + (4 + d) * 150, whhL + (4 + d) * 75, bihL + (4 + d) * 15, bhhL + (4 + d) * 15,
        &S[0][0][0], G, nullptr, nullptr, d, lane);
    __syncthreads();

    // L4: G -> out; fwd runs 30 steps, bwd needs only its first step
    {
        float* op = out + (base + lr) * 10 + d * 5;
        if (d == 0)
            run_layer<false, T, false, true, true>(
                wihL + 6 * 150, whhL + 6 * 75, bihL + 6 * 15, bhhL + 6 * 15,
                G, nullptr, nullptr, op, d, lane);
        else
            run_layer<false, 1, false, true, true>(
                wihL + 7 * 150, whhL + 7 * 75, bihL + 7 * 15, bhhL + 7 * 15,
                G, nullptr, nullptr, op, d, lane);
    }
}

extern "C" void kernel_launch(void* const* d_in, const int* in_sizes, int n_in,
                              void* d_out, int out_size, void* d_ws, size_t ws_size,
                              hipStream_t stream) {
    const float* x    = (const float*)d_in[0];
    const float* wih0 = (const float*)d_in[1];
    const float* whh0 = (const float*)d_in[2];
    const float* bih0 = (const float*)d_in[3];
    const float* bhh0 = (const float*)d_in[4];
    const float* wihL = (const float*)d_in[5];
    const float* whhL = (const float*)d_in[6];
    const float* bihL = (const float*)d_in[7];
    const float* bhhL = (const float*)d_in[8];
    float* out = (float*)d_out;

    gru_all<<<NBLK, 128, 0, stream>>>(x, wih0, whh0, bih0, bhh0,
                                      wihL, whhL, bihL, bhhL, out);
}

// Round 15
// 425.605 us; speedup vs baseline: 1.1687x; 1.1687x over previous
//
#include <hip/hip_runtime.h>

// MFMA-based fully-fused 5-layer bidirectional GRU -- r12 revert + issue
// micro-opts.  (r14 = r13 proposal with the cvt_pkrtz union type fixed:
// the builtin returns __fp16 ext_vector(2), not _Float16 ext_vector(2).)
//
// r13 verdict: dual-chain waves regressed (458us, VALUBusy 57%) -- compiler
// serialized the chains and 2 waves/SIMD lost TLP coverage. Design space now
// bracketed on all axes: r9 occupancy-up = L2 cliff; r10 trans-down-by-
// coupling = slower; r12 deeper prefetch = null; r13 intra-wave ILP = slower.
// r12 (4 single-chain waves/SIMD, 19.2KB LDS + 19.2KB L2-resident G) is the
// constrained optimum. This round: r12 structure exactly, minus issue count:
//  1. DIR-templated layers: sdir/p0/rstep/wstep compile-time (wave-uniform
//     branch per call site; barriers stay at block top level).
//  2. v_cvt_pkrtz_f16_f32 packs (h1,h2) in one instr; seq stores extract
//     from the packed reg (RTZ, <=1 f16 ulp vs RTN; threshold headroom 3x).
//  3. #pragma unroll 2 on step loops for paired offset folding.
//
// Exchange-free B layout (r11, verified): D row = 4u+g -> half0 owns units
// {0,2,4}, half1 {1,3}. B h-slots match ownership: k5,6,7 = h_u0,u2,u4
// (half0 elems 5..7), k13,14 = h_u1,u3 (half1 elems 5..6); x channels at
// k0..4 & k8..12, idx=(k<8?k:k-3), concat col j=(idx&1)*5+(idx>>1). No
// cross-lane h movement. B dwords via 2 layer-constant v_perm + 1 on-chain.
//
// A (32x16 const): row = 4u+g, g in {r,z,i_n,h_n}, rows 20-31 zero; same
// k-rule as B. C = bias fragment, quad q -> u = 2q+half (r2-verified).
// i_n/h_n separate rows so n = tanh(i_n + r*h_n) exact; exp2 scales folded.
//
// Structure (r8/r12): block = 2 waves (wave0 fwd, wave1 bwd), 32 batch cols.
// One 19.2KB LDS buffer + one 19.2KB global buffer (8 blocks/CU, 4.9MB/XCD).
// Dataflow: L0: x->S; L1: S->G; L2: G->S; L3: S->G; L4: G->out (bwd: 1 step).
// Sequences: f16 pair-planes seq[t][unit][batch], fwd lo / bwd hi halfword.

#define NB 262144
#define T 30
#define NBLK (NB / 32)
#define SEQW (T * 5 * 32)          // u32 per per-block sequence buffer

typedef _Float16 f16x8 __attribute__((ext_vector_type(8)));
typedef __fp16 fp16x2 __attribute__((ext_vector_type(2)));   // cvt_pkrtz ret type
typedef float f32x16 __attribute__((ext_vector_type(16)));

__device__ unsigned g_seq[(unsigned long long)NBLK * SEQW];   // 157 MB

#define SIG_SCALE  (-1.4426950408889634f)   // -log2(e)
#define TANH_SCALE ( 2.8853900817779268f)   // 2*log2(e)

__device__ __forceinline__ float sig_s(float xs) {
    // x pre-scaled by -log2e: sigmoid(orig) = 1/(1+2^x)
    return __builtin_amdgcn_rcpf(1.0f + __builtin_amdgcn_exp2f(xs));
}
__device__ __forceinline__ float tanh_s(float xs) {
    // x pre-scaled by 2*log2e: tanh(orig) = 1 - 2/(1+2^x)
    return fmaf(-2.0f, __builtin_amdgcn_rcpf(1.0f + __builtin_amdgcn_exp2f(xs)), 1.0f);
}
__device__ __forceinline__ unsigned hbits(_Float16 a) {
    union { _Float16 f; unsigned short s; } u; u.f = a;
    return (unsigned)u.s;
}
__device__ __forceinline__ unsigned pkrtz(float a, float b) {
    // v_cvt_pkrtz_f16_f32: lo16 = f16(a), hi16 = f16(b), round-toward-zero
    union { fp16x2 h; unsigned u; } x;
    x.h = __builtin_amdgcn_cvt_pkrtz(a, b);
    return x.u;
}

// One direction of one layer. seqR/seqW: [T][5][32] u32 pair-plane buffers
// (LDS or global per G_R); xg: per-block x base (layer 0 only).
// DIR is compile-time: 0 = fwd, 1 = bwd.
template <bool IS_L0, int NT, bool WRITE, bool STORE, bool G_R, int DIR>
__device__ __forceinline__ void run_layer(
    const float* __restrict__ wih, const float* __restrict__ whh,
    const float* __restrict__ bih, const float* __restrict__ bhh,
    const unsigned* seqR, unsigned* seqW, const float* xg,
    float* outp, const int lane)
{
    const int lr   = lane & 31;    // A row / B,D column (batch)
    const int half = lane >> 5;    // k-half for A/B; D-row half bit

    // ---- A fragment: row lr = 4u+g ----
    const int u_r = lr >> 2;
    const int g   = lr & 3;        // 0=r 1=z 2=i_n 3=h_n
    const bool rv = lr < 20;       // rows 20-31 zero

    f16x8 af;
#pragma unroll
    for (int e = 0; e < 8; e++) {
        const int k = 8 * half + e;           // elem e <-> k = 8*half + e
        float v = 0.f;
        if (rv) {
            if (!IS_L0) {
                if (k <= 4 || (k >= 8 && k <= 12)) {      // x channels
                    const int idx = (k < 8) ? k : (k - 3);
                    const int j = (idx & 1) * 5 + (idx >> 1);   // concat col
                    if (g == 0)      v = SIG_SCALE  * wih[u_r * 10 + j];
                    else if (g == 1) v = SIG_SCALE  * wih[(5 + u_r) * 10 + j];
                    else if (g == 2) v = TANH_SCALE * wih[(10 + u_r) * 10 + j];
                } else if (k >= 5 && k <= 7) {            // h_u0,u2,u4
                    const int uh = 2 * (k - 5);
                    if (g == 0)      v = SIG_SCALE  * whh[u_r * 5 + uh];
                    else if (g == 1) v = SIG_SCALE  * whh[(5 + u_r) * 5 + uh];
                    else if (g == 3) v = TANH_SCALE * whh[(10 + u_r) * 5 + uh];
                } else if (k == 13 || k == 14) {          // h_u1,u3
                    const int uh = 2 * (k - 13) + 1;
                    if (g == 0)      v = SIG_SCALE  * whh[u_r * 5 + uh];
                    else if (g == 1) v = SIG_SCALE  * whh[(5 + u_r) * 5 + uh];
                    else if (g == 3) v = TANH_SCALE * whh[(10 + u_r) * 5 + uh];
                }
            } else {
                if (k == 0) {                             // input dim 1
                    if (g == 0)      v = SIG_SCALE  * wih[u_r];
                    else if (g == 1) v = SIG_SCALE  * wih[5 + u_r];
                    else if (g == 2) v = TANH_SCALE * wih[10 + u_r];
                } else if (k >= 5 && k <= 7) {
                    const int uh = 2 * (k - 5);
                    if (g == 0)      v = SIG_SCALE  * whh[u_r * 5 + uh];
                    else if (g == 1) v = SIG_SCALE  * whh[(5 + u_r) * 5 + uh];
                    else if (g == 3) v = TANH_SCALE * whh[(10 + u_r) * 5 + uh];
                } else if (k == 13 || k == 14) {
                    const int uh = 2 * (k - 13) + 1;
                    if (g == 0)      v = SIG_SCALE  * whh[u_r * 5 + uh];
                    else if (g == 1) v = SIG_SCALE  * whh[(5 + u_r) * 5 + uh];
                    else if (g == 3) v = TANH_SCALE * whh[(10 + u_r) * 5 + uh];
                }
            }
        }
        af[e] = (_Float16)v;
    }

    // ---- bias fragment (C): quad q -> unit u = 2q+half (r2-verified) ----
    f32x16 bc;
#pragma unroll
    for (int q = 0; q < 4; q++) {
        const int u = 2 * q + half;
        float b0 = 0.f, b1 = 0.f, b2 = 0.f, b3 = 0.f;
        if (q < 3 && u < 5) {
            b0 = SIG_SCALE  * (bih[u] + bhh[u]);
            b1 = SIG_SCALE  * (bih[5 + u] + bhh[5 + u]);
            b2 = TANH_SCALE * bih[10 + u];
            b3 = TANH_SCALE * bhh[10 + u];
        }
        bc[4 * q + 0] = b0; bc[4 * q + 1] = b1;
        bc[4 * q + 2] = b2; bc[4 * q + 3] = b3;
    }

    // ---- B-assembly selectors (layer-constant; perm: sel<4 -> 2nd arg) ----
    const unsigned S01 = half ? 0x05040302u : 0x03020100u;
    const unsigned S2  = half ? 0x05040302u : 0x05040100u;

    // ---- step state (all strides compile-time via DIR) ----
    constexpr int sdir  = DIR ? -1 : 1;
    constexpr int p0    = DIR ? (T - 1) : 0;
    constexpr int rstep = sdir * 160;
    constexpr int wstep = sdir * 320;
    // half0 reads planes 0,1,2; half1 reads planes 2,3,4 (offsets 0/32/64)
    const unsigned* rbase = seqR + p0 * 160 + lr + (half ? 64 : 0);
    _Float16* wbase = (_Float16*)seqW + p0 * 320 + lr * 2 + DIR;

    // h0 = u(half), h1 = u(2+half), h2 = u4 (half0; dead on half1)
    float h0 = 0.f, h1 = 0.f, h2 = 0.f;
    unsigned hw2 = 0, hw3 = 0;     // h0 bits (low16); pkrtz(h1,h2)

    auto step = [&](unsigned pa, unsigned pb, unsigned pc, unsigned xv) {
        union { f16x8 v; unsigned u[4]; } B;
        if constexpr (!IS_L0) {
            B.u[0] = __builtin_amdgcn_perm(pb, pa, S01);
            B.u[1] = __builtin_amdgcn_perm(pc, pb, S01);
            B.u[2] = __builtin_amdgcn_perm(hw2, pc, S2);
        } else {
            B.u[0] = half ? 0u : xv;
            B.u[1] = 0u;
            B.u[2] = hw2 << 16;            // (0, h0)
        }
        B.u[3] = hw3;                      // (h1, h2); dead k-rows are 0 in A

        const f32x16 D = __builtin_amdgcn_mfma_f32_32x32x16_f16(af, B.v, bc, 0, 0, 0);

        // activations (independent chains): quad q = unit 2q+half
        float r, z, n;
        r = sig_s(D[0]); z = sig_s(D[1]);
        n = tanh_s(fmaf(r, D[3], D[2]));
        h0 = fmaf(z, h0 - n, n);
        r = sig_s(D[4]); z = sig_s(D[5]);
        n = tanh_s(fmaf(r, D[7], D[6]));
        h1 = fmaf(z, h1 - n, n);
        r = sig_s(D[8]); z = sig_s(D[9]);
        n = tanh_s(fmaf(r, D[11], D[10]));
        h2 = fmaf(z, h2 - n, n);           // zero rows on half1: harmless 0

        const _Float16 q0f = (_Float16)h0;     // RTN (1 cvt)
        hw2 = hbits(q0f);
        hw3 = pkrtz(h1, h2);                   // 1 instr packs both

        if constexpr (WRITE) {
            wbase[half * 64] = q0f;                              // plane u=half
            *(unsigned short*)&wbase[(2 + half) * 64] =
                (unsigned short)hw3;                             // plane u=2+half
            if (!half)
                *(unsigned short*)&wbase[4 * 64] =
                    (unsigned short)(hw3 >> 16);                 // plane u=4
            wbase += wstep;
        }
    };

    if constexpr (IS_L0) {
        // x direct from global, 2-step prefetch
        const float* xp = xg + lr * T + p0;
        float xf0 = xp[0];
        float xf1 = (NT > 1) ? xp[sdir] : 0.f;
        xp += 2 * sdir;
#pragma unroll 2
        for (int s = 0; s < NT; s++) {
            const unsigned xv = hbits((_Float16)xf0);
            xf0 = xf1;
            if (s + 2 < NT) { xf1 = *xp; xp += sdir; }
            step(0u, 0u, 0u, xv);
        }
    } else if constexpr (!G_R) {
        // LDS reads, 1-step prefetch
        const unsigned* rb = rbase;
        unsigned a0 = rb[0], a1 = rb[32], a2 = rb[64];
#pragma unroll 2
        for (int s = 0; s < NT; s++) {
            const unsigned t0 = a0, t1 = a1, t2 = a2;
            if (s + 1 < NT) {
                rb += rstep;
                a0 = rb[0]; a1 = rb[32]; a2 = rb[64];
            }
            step(t0, t1, t2, 0u);
        }
    } else if constexpr (NT == 1) {
        // layer-4 bwd: single step
        step(rbase[0], rbase[32], rbase[64], 0u);
    } else {
        // global reads: FOUR reg sets, prefetch 4 positions ahead (vmcnt)
        const unsigned* rn = rbase;
        unsigned a0 = rn[0], a1 = rn[32], a2 = rn[64]; rn += rstep;
        unsigned b0 = rn[0], b1 = rn[32], b2 = rn[64]; rn += rstep;
        unsigned c0 = rn[0], c1 = rn[32], c2 = rn[64]; rn += rstep;
        unsigned e0 = rn[0], e1 = rn[32], e2 = rn[64]; rn += rstep;
        for (int s = 0; s < NT; s += 4) {
            step(a0, a1, a2, 0u);
            if (s + 4 < NT) { a0 = rn[0]; a1 = rn[32]; a2 = rn[64]; rn += rstep; }
            if (s + 1 < NT) {
                step(b0, b1, b2, 0u);
                if (s + 5 < NT) { b0 = rn[0]; b1 = rn[32]; b2 = rn[64]; rn += rstep; }
            }
            if (s + 2 < NT) {
                step(c0, c1, c2, 0u);
                if (s + 6 < NT) { c0 = rn[0]; c1 = rn[32]; c2 = rn[64]; rn += rstep; }
            }
            if (s + 3 < NT) {
                step(e0, e1, e2, 0u);
                if (s + 7 < NT) { e0 = rn[0]; e1 = rn[32]; e2 = rn[64]; rn += rstep; }
            }
        }
    }

    if constexpr (STORE) {               // ys[T-1] for this direction
        outp[half]     = h0;
        outp[2 + half] = h1;
        if (!half) outp[4] = h2;
    }
}

__global__ void __launch_bounds__(128, 4) gru_all(
    const float* __restrict__ x,
    const float* __restrict__ wih0, const float* __restrict__ whh0,
    const float* __restrict__ bih0, const float* __restrict__ bhh0,
    const float* __restrict__ wihL, const float* __restrict__ whhL,
    const float* __restrict__ bihL, const float* __restrict__ bhhL,
    float* __restrict__ out)
{
    __shared__ unsigned S[T][5][32];             // 19200 B -> 8 blocks/CU

    const int tid  = threadIdx.x;
    const int d    = tid >> 6;                   // wave0 = fwd, wave1 = bwd
    const int lane = tid & 63;
    const int lr   = lane & 31;
    const long base = (long)blockIdx.x * 32;

    const float* xg = x + base * T;
    unsigned* G = g_seq + (unsigned long long)blockIdx.x * SEQW;

    // L0: x -> S   (branch is wave-uniform; barriers stay at block level)
    if (d == 0)
        run_layer<true, T, true, false, false, 0>(
            wih0, whh0, bih0, bhh0, nullptr, &S[0][0][0], xg, nullptr, lane);
    else
        run_layer<true, T, true, false, false, 1>(
            wih0 + 15, whh0 + 75, bih0 + 15, bhh0 + 15,
            nullptr, &S[0][0][0], xg, nullptr, lane);
    __syncthreads();

    // L1: S -> G
    if (d == 0)
        run_layer<false, T, true, false, false, 0>(
            wihL, whhL, bihL, bhhL, &S[0][0][0], G, nullptr, nullptr, lane);
    else
        run_layer<false, T, true, false, false, 1>(
            wihL + 150, whhL + 75, bihL + 15, bhhL + 15,
            &S[0][0][0], G, nullptr, nullptr, lane);
    __syncthreads();

    // L2: G -> S
    if (d == 0)
        run_layer<false, T, true, false, true, 0>(
            wihL + 2 * 150, whhL + 2 * 75, bihL + 2 * 15, bhhL + 2 * 15,
            G, &S[0][0][0], nullptr, nullptr, lane);
    else
        run_layer<false, T, true, false, true, 1>(
            wihL + 3 * 150, whhL + 3 * 75, bihL + 3 * 15, bhhL + 3 * 15,
            G, &S[0][0][0], nullptr, nullptr, lane);
    __syncthreads();

    // L3: S -> G
    if (d == 0)
        run_layer<false, T, true, false, false, 0>(
            wihL + 4 * 150, whhL + 4 * 75, bihL + 4 * 15, bhhL + 4 * 15,
            &S[0][0][0], G, nullptr, nullptr, lane);
    else
        run_layer<false, T, true, false, false, 1>(
            wihL + 5 * 150, whhL + 5 * 75, bihL + 5 * 15, bhhL + 5 * 15,
            &S[0][0][0], G, nullptr, nullptr, lane);
    __syncthreads();

    // L4: G -> out; fwd runs 30 steps, bwd needs only its first step
    {
        float* op = out + (base + lr) * 10 + d * 5;
        if (d == 0)
            run_layer<false, T, false, true, true, 0>(
                wihL + 6 * 150, whhL + 6 * 75, bihL + 6 * 15, bhhL + 6 * 15,
                G, nullptr, nullptr, op, lane);
        else
            run_layer<false, 1, false, true, true, 1>(
                wihL + 7 * 150, whhL + 7 * 75, bihL + 7 * 15, bhhL + 7 * 15,
                G, nullptr, nullptr, op, lane);
    }
}

extern "C" void kernel_launch(void* const* d_in, const int* in_sizes, int n_in,
                              void* d_out, int out_size, void* d_ws, size_t ws_size,
                              hipStream_t stream) {
    const float* x    = (const float*)d_in[0];
    const float* wih0 = (const float*)d_in[1];
    const float* whh0 = (const float*)d_in[2];
    const float* bih0 = (const float*)d_in[3];
    const float* bhh0 = (const float*)d_in[4];
    const float* wihL = (const float*)d_in[5];
    const float* whhL = (const float*)d_in[6];
    const float* bihL = (const float*)d_in[7];
    const float* bhhL = (const float*)d_in[8];
    float* out = (float*)d_out;

    gru_all<<<NBLK, 128, 0, stream>>>(x, wih0, whh0, bih0, bhh0,
                                      wihL, whhL, bihL, bhhL, out);
}